// Round 1
// baseline (11275.153 us; speedup 1.0000x reference)
//
#include <hip/hip_runtime.h>
#include <stdint.h>
#include <stddef.h>

#define T_SEQ 256
#define BATCH 64
#define HID   1024
#define GATES 4096

typedef __bf16 bf16_t;
typedef __bf16 bf16x8 __attribute__((ext_vector_type(8)));
typedef float  f32x4  __attribute__((ext_vector_type(4)));

__device__ __forceinline__ f32x4 mfma_bf16(bf16x8 a, bf16x8 b, f32x4 c) {
    return __builtin_amdgcn_mfma_f32_16x16x32_bf16(a, b, c, 0, 0, 0);
}

__device__ __forceinline__ void gld_lds16(const bf16_t* g, bf16_t* l) {
    __builtin_amdgcn_global_load_lds((const __attribute__((address_space(1))) void*)g,
                                     (__attribute__((address_space(3))) void*)l, 16, 0, 0);
}

__device__ __forceinline__ float sigm(float x) { return 1.0f / (1.0f + __expf(-x)); }

// ---------------- conversion kernels ----------------

__global__ void cvt_f32_bf16(const float* __restrict__ src, bf16_t* __restrict__ dst, int n) {
    int i = (blockIdx.x * 256 + threadIdx.x) * 4;
    if (i + 3 < n) {
        float4 v = *(const float4*)(src + i);
        dst[i + 0] = (bf16_t)v.x; dst[i + 1] = (bf16_t)v.y;
        dst[i + 2] = (bf16_t)v.z; dst[i + 3] = (bf16_t)v.w;
    }
}

__global__ void cvt_split_bf16(const float* __restrict__ src, bf16_t* __restrict__ hi,
                               bf16_t* __restrict__ lo, int n) {
    int i = (blockIdx.x * 256 + threadIdx.x) * 4;
    if (i + 3 < n) {
        float4 v = *(const float4*)(src + i);
        float f0 = v.x, f1 = v.y, f2 = v.z, f3 = v.w;
        bf16_t h0 = (bf16_t)f0, h1 = (bf16_t)f1, h2 = (bf16_t)f2, h3 = (bf16_t)f3;
        hi[i + 0] = h0; hi[i + 1] = h1; hi[i + 2] = h2; hi[i + 3] = h3;
        lo[i + 0] = (bf16_t)(f0 - (float)h0);
        lo[i + 1] = (bf16_t)(f1 - (float)h1);
        lo[i + 2] = (bf16_t)(f2 - (float)h2);
        lo[i + 3] = (bf16_t)(f3 - (float)h3);
    }
}

__global__ void bias_sum(const float* __restrict__ a, const float* __restrict__ b,
                         float* __restrict__ o) {
    int i = blockIdx.x * 256 + threadIdx.x;   // grid covers exactly 4096
    o[i] = a[i] + b[i];
}

__global__ void zero_state(float* __restrict__ c, bf16_t* __restrict__ h0) {
    int i = blockIdx.x * 256 + threadIdx.x;   // grid covers exactly 2*64*1024
    c[i] = 0.0f;
    h0[i] = (bf16_t)0.0f;
}

__global__ void copy_last(const float* __restrict__ src, float* __restrict__ dst) {
    int i = blockIdx.x * 256 + threadIdx.x;   // grid covers exactly 256*2048
    dst[i] = src[i];
}

// ---------------- projection GEMM ----------------
// C[m_eff, n] = A[row(m_eff), 0:K] . W[n, 0:K]  (+bsum[n])  -> P[tt, b, n]
// m_eff = b*Tc + tt, row = b*T_SEQ + t_base + tt.
// 128x128 tile per 256-thread WG; 4 waves in 2x2; each wave 4x4 frags of 16x16x32.
__global__ __launch_bounds__(256)
void proj_gemm(const bf16_t* __restrict__ A, int K,
               const bf16_t* __restrict__ W,
               const float* __restrict__ bsum,
               float* __restrict__ P,
               int Tc_log2, int t_base, int accum)
{
    __shared__ __align__(16) bf16_t As[128 * 32];
    __shared__ __align__(16) bf16_t Bs[128 * 32];

    const int tid  = threadIdx.x;
    const int lane = tid & 63;
    const int wv   = tid >> 6;
    const int wm   = wv >> 1;
    const int wn   = wv & 1;

    const int Tc    = 1 << Tc_log2;
    const int tileM = blockIdx.x;
    const int tileN = blockIdx.y;

    // staging roles: idx = rep*256 + tid ; row = idx>>2 ; 16B segment = idx&3
    const int srow = tid >> 2;
    const int sseg = tid & 3;

    int me0 = tileM * 128 + srow;
    int me1 = me0 + 64;
    int b0 = me0 >> Tc_log2, tt0 = me0 & (Tc - 1);
    int b1 = me1 >> Tc_log2, tt1 = me1 & (Tc - 1);
    const bf16_t* gA0 = A + (size_t)(b0 * T_SEQ + t_base + tt0) * K + sseg * 8;
    const bf16_t* gA1 = A + (size_t)(b1 * T_SEQ + t_base + tt1) * K + sseg * 8;
    const bf16_t* gB0 = W + (size_t)(tileN * 128 + srow) * K + sseg * 8;
    const bf16_t* gB1 = W + (size_t)(tileN * 128 + 64 + srow) * K + sseg * 8;

    // wave-uniform LDS bases (elements): chunk (rep,wv) starts at (rep*256+wv*64)*8
    bf16_t* lA0 = As + (size_t)(wv * 64) * 8;
    bf16_t* lA1 = As + (size_t)(256 + wv * 64) * 8;
    bf16_t* lB0 = Bs + (size_t)(wv * 64) * 8;
    bf16_t* lB1 = Bs + (size_t)(256 + wv * 64) * 8;

    f32x4 acc[4][4] = {};

    const int rbase = lane & 15;
    const int k8    = (lane >> 4) * 8;

    for (int ks = 0; ks < K; ks += 32) {
        gld_lds16(gA0 + ks, lA0);
        gld_lds16(gA1 + ks, lA1);
        gld_lds16(gB0 + ks, lB0);
        gld_lds16(gB1 + ks, lB1);
        __syncthreads();

        bf16x8 af[4], bfr[4];
        #pragma unroll
        for (int m = 0; m < 4; ++m)
            af[m] = *(const bf16x8*)&As[(wm * 64 + m * 16 + rbase) * 32 + k8];
        #pragma unroll
        for (int n = 0; n < 4; ++n)
            bfr[n] = *(const bf16x8*)&Bs[(wn * 64 + n * 16 + rbase) * 32 + k8];
        #pragma unroll
        for (int m = 0; m < 4; ++m)
            #pragma unroll
            for (int n = 0; n < 4; ++n)
                acc[m][n] = mfma_bf16(af[m], bfr[n], acc[m][n]);
        __syncthreads();
    }

    #pragma unroll
    for (int n = 0; n < 4; ++n) {
        int col = tileN * 128 + wn * 64 + n * 16 + rbase;
        float bv = bsum[col];
        #pragma unroll
        for (int m = 0; m < 4; ++m) {
            #pragma unroll
            for (int j = 0; j < 4; ++j) {
                int me = tileM * 128 + wm * 64 + m * 16 + (lane >> 4) * 4 + j;
                int bb = me >> Tc_log2;
                int tt = me & (Tc - 1);
                size_t idx = (size_t)(tt * BATCH + bb) * GATES + col;
                float base = accum ? P[idx] : bv;
                P[idx] = base + acc[m][n][j];
            }
        }
    }
}

// ---------------- recurrence step ----------------
// grid.x = 256: dir = blk>>7, hidden slice of 8 = (blk&127)*8.
// Per WG: gates[64,32] = hprev[64,1024] . Whh_slice^T  (cols: i(8) f(8) g(8) o(8))
// then pointwise LSTM cell; c fp32 in ws; h bf16 double-buffered.
__global__ __launch_bounds__(256)
void lstm_step(const bf16_t* __restrict__ Whf,
               const bf16_t* __restrict__ Whb,
               const float* __restrict__ Pf,
               const float* __restrict__ Pb,
               const bf16_t* __restrict__ hprev,  // [2][64][1024]
               bf16_t* __restrict__ hnext,        // [2][64][1024]
               float* __restrict__ c_state,       // [2][64][1024]
               bf16_t* __restrict__ hcat,         // layer0 output (or null)
               float* __restrict__ fout,          // layer1 output (or null)
               int t_fwd, int pt_f, int pt_b)
{
    const int dir   = blockIdx.x >> 7;
    const int hbase = (blockIdx.x & 127) * 8;
    const bf16_t* W = dir ? Whb : Whf;
    const float*  P = dir ? Pb  : Pf;
    const int     pt = dir ? pt_b : pt_f;
    const bf16_t* hp = hprev + (size_t)dir * (BATCH * HID);

    const int tid   = threadIdx.x;
    const int lane  = tid & 63;
    const int wv    = tid >> 6;
    const int rbase = lane & 15;
    const int k8    = (lane >> 4) * 8;

    // W rows for B-frags: frag0 cols 0..15 -> gate blocks 0,1 ; frag1 cols 16..31 -> 2,3
    const int cA = rbase;
    const int cB = 16 + rbase;
    const bf16_t* Wr0 = W + (size_t)((cA >> 3) * HID + hbase + (cA & 7)) * HID + k8;
    const bf16_t* Wr1 = W + (size_t)((cB >> 3) * HID + hbase + (cB & 7)) * HID + k8;
    const bf16_t* Ar  = hp + (size_t)(wv * 16 + rbase) * HID + k8;

    f32x4 acc0 = {}, acc1 = {};
    #pragma unroll 8
    for (int k = 0; k < HID; k += 32) {
        bf16x8 a  = *(const bf16x8*)(Ar + k);
        bf16x8 w0 = *(const bf16x8*)(Wr0 + k);
        bf16x8 w1 = *(const bf16x8*)(Wr1 + k);
        acc0 = mfma_bf16(a, w0, acc0);
        acc1 = mfma_bf16(a, w1, acc1);
    }

    __shared__ float gl[64][32];
    #pragma unroll
    for (int j = 0; j < 4; ++j) {
        gl[wv * 16 + (lane >> 4) * 4 + j][rbase]      = acc0[j];
        gl[wv * 16 + (lane >> 4) * 4 + j][16 + rbase] = acc1[j];
    }
    __syncthreads();

    const int t = dir ? (T_SEQ - 1 - t_fwd) : t_fwd;
    #pragma unroll
    for (int it = tid; it < 512; it += 256) {
        int b  = it >> 3, kk = it & 7;
        int hk = hbase + kk;
        const float* Prow = P + (size_t)(pt * BATCH + b) * GATES;
        float gi = gl[b][kk]      + Prow[hk];
        float gf = gl[b][8 + kk]  + Prow[HID + hk];
        float gg = gl[b][16 + kk] + Prow[2 * HID + hk];
        float go = gl[b][24 + kk] + Prow[3 * HID + hk];
        float* cp = c_state + (size_t)(dir * BATCH + b) * HID + hk;
        float cn = sigm(gf) * (*cp) + sigm(gi) * tanhf(gg);
        float h  = sigm(go) * tanhf(cn);
        *cp = cn;
        hnext[(size_t)(dir * BATCH + b) * HID + hk] = (bf16_t)h;
        size_t oidx = (size_t)(b * T_SEQ + t) * (2 * HID) + (size_t)dir * HID + hk;
        if (fout) fout[oidx] = h;
        else      hcat[oidx] = (bf16_t)h;
    }
}

// ---------------- host ----------------

extern "C" void kernel_launch(void* const* d_in, const int* in_sizes, int n_in,
                              void* d_out, int out_size, void* d_ws, size_t ws_size,
                              hipStream_t stream)
{
    (void)in_sizes; (void)n_in; (void)out_size;

    const float* x = (const float*)d_in[0];
    // [dir][layer]
    const float* wih[2][2] = { { (const float*)d_in[1],  (const float*)d_in[5]  },
                               { (const float*)d_in[9],  (const float*)d_in[13] } };
    const float* whh[2][2] = { { (const float*)d_in[2],  (const float*)d_in[6]  },
                               { (const float*)d_in[10], (const float*)d_in[14] } };
    const float* bih[2][2] = { { (const float*)d_in[3],  (const float*)d_in[7]  },
                               { (const float*)d_in[11], (const float*)d_in[15] } };
    const float* bhh[2][2] = { { (const float*)d_in[4],  (const float*)d_in[8]  },
                               { (const float*)d_in[12], (const float*)d_in[16] } };

    const size_t N_X  = (size_t)BATCH * T_SEQ * 512;
    const size_t N_W0 = (size_t)GATES * 512;
    const size_t N_W1 = (size_t)GATES * 2048;
    const size_t N_WH = (size_t)GATES * HID;
    const size_t N_HC = (size_t)BATCH * T_SEQ * 2 * HID;
    const size_t N_ST = (size_t)2 * BATCH * HID;

    char* ws = (char*)d_ws;
    size_t off = 0;
    auto alloc = [&](size_t bytes) -> void* {
        void* p = ws + off;
        off += (bytes + 255) & ~(size_t)255;
        return p;
    };

    bf16_t* wih_hi[2][2];
    bf16_t* wih_lo0[2];     // layer-0 W_ih lo part
    bf16_t* whh_bf[2][2];
    float*  bs[2][2];
    for (int d = 0; d < 2; ++d) {
        wih_hi[d][0] = (bf16_t*)alloc(N_W0 * 2);
        wih_lo0[d]   = (bf16_t*)alloc(N_W0 * 2);
        wih_hi[d][1] = (bf16_t*)alloc(N_W1 * 2);
        whh_bf[d][0] = (bf16_t*)alloc(N_WH * 2);
        whh_bf[d][1] = (bf16_t*)alloc(N_WH * 2);
        bs[d][0]     = (float*)alloc(GATES * 4);
        bs[d][1]     = (float*)alloc(GATES * 4);
    }
    bf16_t* x_hi  = (bf16_t*)alloc(N_X * 2);
    bf16_t* x_lo  = (bf16_t*)alloc(N_X * 2);
    bf16_t* hcat0 = (bf16_t*)alloc(N_HC * 2);
    bf16_t* hb0   = (bf16_t*)alloc(N_ST * 2);
    bf16_t* hb1   = (bf16_t*)alloc(N_ST * 2);
    float*  c_st  = (float*)alloc(N_ST * 4);

    // choose largest power-of-two time chunk whose two fp32 P buffers fit
    int Tc = 256;
    while (Tc > 2) {
        size_t need = off + 2 * ((size_t)Tc * BATCH * GATES * 4 + 256);
        if (need <= ws_size) break;
        Tc >>= 1;
    }
    int Tclog2 = __builtin_ctz((unsigned)Tc);
    float* Pf = (float*)alloc((size_t)Tc * BATCH * GATES * 4);
    float* Pb = (float*)alloc((size_t)Tc * BATCH * GATES * 4);

    // ---- conversions ----
    cvt_split_bf16<<<(int)(N_X / 1024), 256, 0, stream>>>(x, x_hi, x_lo, (int)N_X);
    for (int d = 0; d < 2; ++d) {
        cvt_split_bf16<<<(int)(N_W0 / 1024), 256, 0, stream>>>(wih[d][0], wih_hi[d][0], wih_lo0[d], (int)N_W0);
        cvt_f32_bf16<<<(int)(N_W1 / 1024), 256, 0, stream>>>(wih[d][1], wih_hi[d][1], (int)N_W1);
        cvt_f32_bf16<<<(int)(N_WH / 1024), 256, 0, stream>>>(whh[d][0], whh_bf[d][0], (int)N_WH);
        cvt_f32_bf16<<<(int)(N_WH / 1024), 256, 0, stream>>>(whh[d][1], whh_bf[d][1], (int)N_WH);
        bias_sum<<<16, 256, 0, stream>>>(bih[d][0], bhh[d][0], bs[d][0]);
        bias_sum<<<16, 256, 0, stream>>>(bih[d][1], bhh[d][1], bs[d][1]);
    }

    float* out0 = (float*)d_out;

    for (int l = 0; l < 2; ++l) {
        const int K = l ? 2048 : 512;
        zero_state<<<(int)(N_ST / 256), 256, 0, stream>>>(c_st, hb0);
        for (int t0 = 0; t0 < T_SEQ; t0 += Tc) {
            dim3 g((BATCH * Tc) / 128, GATES / 128);
            int tb_f = t0;
            int tb_b = T_SEQ - t0 - Tc;
            if (l == 0) {
                proj_gemm<<<g, 256, 0, stream>>>(x_hi, K, wih_hi[0][0], bs[0][0], Pf, Tclog2, tb_f, 0);
                proj_gemm<<<g, 256, 0, stream>>>(x_lo, K, wih_hi[0][0], bs[0][0], Pf, Tclog2, tb_f, 1);
                proj_gemm<<<g, 256, 0, stream>>>(x_hi, K, wih_lo0[0],  bs[0][0], Pf, Tclog2, tb_f, 1);
                proj_gemm<<<g, 256, 0, stream>>>(x_hi, K, wih_hi[1][0], bs[1][0], Pb, Tclog2, tb_b, 0);
                proj_gemm<<<g, 256, 0, stream>>>(x_lo, K, wih_hi[1][0], bs[1][0], Pb, Tclog2, tb_b, 1);
                proj_gemm<<<g, 256, 0, stream>>>(x_hi, K, wih_lo0[1],  bs[1][0], Pb, Tclog2, tb_b, 1);
            } else {
                proj_gemm<<<g, 256, 0, stream>>>(hcat0, K, wih_hi[0][1], bs[0][1], Pf, Tclog2, tb_f, 0);
                proj_gemm<<<g, 256, 0, stream>>>(hcat0, K, wih_hi[1][1], bs[1][1], Pb, Tclog2, tb_b, 0);
            }
            for (int s = t0; s < t0 + Tc; ++s) {
                bf16_t* hp = (s & 1) ? hb1 : hb0;
                bf16_t* hn = (s & 1) ? hb0 : hb1;
                lstm_step<<<256, 256, 0, stream>>>(whh_bf[0][l], whh_bf[1][l], Pf, Pb,
                                                   hp, hn, c_st,
                                                   l ? (bf16_t*)nullptr : hcat0,
                                                   l ? out0 : (float*)nullptr,
                                                   s, s - t0, Tc - 1 - (s - t0));
            }
        }
    }

    copy_last<<<(T_SEQ * 2 * HID) / 256, 256, 0, stream>>>(
        out0 + (size_t)(BATCH - 1) * T_SEQ * 2 * HID,
        out0 + (size_t)BATCH * T_SEQ * 2 * HID);
}